// Round 21
// baseline (186.076 us; speedup 1.0000x reference)
//
#include <hip/hip_runtime.h>

#define NN 100000
#define NE 1600000
#define FI 128
#define FH 64
#define FO 40
#define NR 500      // dst ranges
#define RSZ 200     // nodes per range (NR*RSZ == NN)
#define NBK 512     // histogram/scatter blocks

typedef _Float16 f16;
typedef _Float16 f16x2 __attribute__((ext_vector_type(2)));

// ---------------- Threefry-2x32, key = (0, 42) -----------------------------
__device__ __forceinline__ unsigned rotl32(unsigned v, unsigned r) {
    return (v << r) | (v >> (32u - r));
}

__device__ __forceinline__ void threefry_0_42(unsigned x0, unsigned x1,
                                              unsigned& o0, unsigned& o1) {
    const unsigned k0 = 0u, k1 = 42u;
    const unsigned k2 = 0x1BD11BDAu ^ k0 ^ k1;
    x0 += k0; x1 += k1;
#define TFR(r) { x0 += x1; x1 = rotl32(x1, r); x1 ^= x0; }
    TFR(13) TFR(15) TFR(26) TFR(6)   x0 += k1; x1 += k2 + 1u;
    TFR(17) TFR(29) TFR(16) TFR(24)  x0 += k2; x1 += k0 + 2u;
    TFR(13) TFR(15) TFR(26) TFR(6)   x0 += k0; x1 += k1 + 3u;
    TFR(17) TFR(29) TFR(16) TFR(24)  x0 += k1; x1 += k2 + 4u;
    TFR(13) TFR(15) TFR(26) TFR(6)   x0 += k2; x1 += k0 + 5u;
#undef TFR
    o0 = x0; o1 = x1;
}

__device__ __forceinline__ void unpack2(unsigned u, float& lo, float& hi) {
    union { unsigned u; f16 h[2]; } c;
    c.u = u;
    lo = (float)c.h[0];
    hi = (float)c.h[1];
}

// select one of 4 wave-uniform values by per-lane parity p (0..3)
__device__ __forceinline__ int sel4(int p, int s0, int s1, int s2, int s3) {
    int t0 = (p & 1) ? s1 : s0;
    int t1 = (p & 1) ? s3 : s2;
    return (p & 2) ? t1 : t0;
}

// ---------------- k_mask: precompute dropout keep-mask (u64 per node) ------
__global__ __launch_bounds__(256) void k_mask(unsigned long long* __restrict__ dm) {
    int tid = blockIdx.x * 256 + threadIdx.x;   // element = node*64 + feature
    unsigned o0, o1;
    threefry_0_42(0u, (unsigned)tid, o0, o1);
    unsigned long long m = __ballot((int)(((o0 ^ o1) >> 31) ^ 1u));
    if ((threadIdx.x & 63) == 0) dm[tid >> 6] = m;
}

// ---------------- P1: per-block LDS range histogram (2 edges/thread) -------
__global__ __launch_bounds__(256) void k_p1(const int* __restrict__ ei,
                                            int* __restrict__ blkhist) {
    __shared__ int h[NR];
    int t = threadIdx.x, b = blockIdx.x;
    for (int i = t; i < NR; i += 256) h[i] = 0;
    __syncthreads();
    for (int base = b * 512 + t * 2; base < NE; base += NBK * 512) {
        int2 dd = *(const int2*)&ei[NE + base];
        atomicAdd(&h[dd.x / RSZ], 1);            // LDS atomic
        atomicAdd(&h[dd.y / RSZ], 1);
    }
    __syncthreads();
    for (int i = t; i < NR; i += 256) blkhist[(size_t)b * NR + i] = h[i];
}

// ---------------- scanR1: per-range exclusive scan over blocks -------------
__global__ __launch_bounds__(512) void k_scanR1(int* __restrict__ blkhist,
                                                int* __restrict__ rtot) {
    __shared__ int sh[NBK];
    int r = blockIdx.x, t = threadIdx.x;
    int v = blkhist[(size_t)t * NR + r];
    sh[t] = v;
    __syncthreads();
    for (int off = 1; off < NBK; off <<= 1) {
        int u = (t >= off) ? sh[t - off] : 0;
        __syncthreads();
        sh[t] += u;
        __syncthreads();
    }
    blkhist[(size_t)t * NR + r] = sh[t] - v;     // block-local prefix
    if (t == NBK - 1) rtot[r] = sh[t];
}

// ---------------- scanR2: exclusive scan of range totals -------------------
__global__ __launch_bounds__(512) void k_scanR2(const int* __restrict__ rtot,
                                                int* __restrict__ rangeBase) {
    __shared__ int sh[512];
    int t = threadIdx.x;
    int v = (t < NR) ? rtot[t] : 0;
    sh[t] = v;
    __syncthreads();
    for (int off = 1; off < 512; off <<= 1) {
        int u = (t >= off) ? sh[t - off] : 0;
        __syncthreads();
        sh[t] += u;
        __syncthreads();
    }
    if (t < NR) rangeBase[t] = sh[t] - v;
    if (t == NR - 1) rangeBase[NR] = sh[t];      // == NE
}

// ---------------- P2: scatter edges, packed 4B (dloc<<17 | src) ------------
__global__ __launch_bounds__(256) void k_p2(const int* __restrict__ ei,
                                            const int* __restrict__ blkhist,
                                            const int* __restrict__ rangeBase,
                                            int* __restrict__ bucket) {
    __shared__ int cur[NR];
    int t = threadIdx.x, b = blockIdx.x;
    for (int i = t; i < NR; i += 256)
        cur[i] = rangeBase[i] + blkhist[(size_t)b * NR + i];
    __syncthreads();
    for (int base = b * 512 + t * 2; base < NE; base += NBK * 512) {  // same slice as k_p1
        int2 ss = *(const int2*)&ei[base];
        int2 dd = *(const int2*)&ei[NE + base];
        int rg0 = dd.x / RSZ;
        int rg1 = dd.y / RSZ;
        int pos0 = atomicAdd(&cur[rg0], 1);               // LDS atomic
        bucket[pos0] = ((dd.x - rg0 * RSZ) << 17) | ss.x;
        int pos1 = atomicAdd(&cur[rg1], 1);
        bucket[pos1] = ((dd.y - rg1 * RSZ) << 17) | ss.y;
    }
}

// ---------------- P3: per-range CSR finalize, segments padded to x4 --------
// Padded entries point to src = NN (all-zero feature row) -> tail-free agg.
__global__ __launch_bounds__(256) void k_p3(const int* __restrict__ bucket,
                                            const int* __restrict__ rangeBase,
                                            int2* __restrict__ odpk,
                                            float* __restrict__ inv,
                                            int* __restrict__ csr_s) {
    __shared__ int cnt[RSZ];
    __shared__ int base[RSZ];
    __shared__ int sc[256];
    int r = blockIdx.x, t = threadIdx.x;
    int e0 = rangeBase[r], e1 = rangeBase[r + 1];
    int padBase = e0 + 3 * RSZ * r;                       // padded global base
    int n0 = r * RSZ;
    if (t < RSZ) cnt[t] = 0;
    __syncthreads();
    for (int i = e0 + t; i < e1; i += 256)
        atomicAdd(&cnt[((unsigned)bucket[i]) >> 17], 1);  // LDS atomic
    __syncthreads();
    int v = 0, vp = 0;
    if (t < RSZ) {
        v = cnt[t];
        vp = (v + 3) & ~3;                                // padded count
    }
    sc[t] = vp;
    __syncthreads();
    for (int off = 1; off < 256; off <<= 1) {
        int u = (t >= off) ? sc[t - off] : 0;
        __syncthreads();
        sc[t] += u;
        __syncthreads();
    }
    int o = 0;
    if (t < RSZ) {
        o = padBase + sc[t] - vp;                         // padded CSR offset
        odpk[n0 + t] = make_int2(o, vp);                  // loop bound = padded
        inv[n0 + t] = rsqrtf((float)v + 1.0f);            // norm from real deg
        base[t] = o;                                      // cursor start
    }
    __syncthreads();
    for (int i = e0 + t; i < e1; i += 256) {
        int pk = bucket[i];
        int dloc = ((unsigned)pk) >> 17;
        int p = atomicAdd(&base[dloc], 1);                // LDS atomic
        csr_s[p] = pk & 0x1FFFF;
    }
    __syncthreads();
    if (t < RSZ) {
        for (int j = v; j < vp; ++j) csr_s[o + j] = NN;   // sentinel pads
    }
}

// ---------------- GEMM1: h0s[N,64] = (x @ W1) * inv[row] (fp16, +zero row) -
// x staged in two 64-col halves -> LDS 33.4 KB -> 4 blocks/CU.
#define XS_STRIDE 68    // 64 + 4: b128-aligned, rows on distinct banks
__global__ __launch_bounds__(256) void k_gemm1(const float* __restrict__ x,
                                               const float* __restrict__ W1,
                                               const float* __restrict__ inv,
                                               f16* __restrict__ h0s) {
    __shared__ float xs[64 * XS_STRIDE];   // 17.4 KB (one K-half of x tile)
    __shared__ float ws[64 * FH];          // 16 KB (one K-half of W1)
    int t = threadIdx.x;
    int row0 = blockIdx.x * 64;
    float acc[4][4] = {{0.f}};
    int tx4 = (t & 15) * 4;
    int ty4 = (t >> 4) * 4;
    int sr = t >> 4;              // 0..15
    int sc4 = (t & 15) * 4;       // 0..60
#pragma unroll
    for (int half = 0; half < 2; ++half) {
        __syncthreads();
#pragma unroll
        for (int p = 0; p < 4; ++p) {
            int row = row0 + sr + p * 16;
            float4 v = make_float4(0.f, 0.f, 0.f, 0.f);
            if (row < NN) v = *(const float4*)&x[(size_t)row * FI + half * 64 + sc4];
            *(float4*)&xs[(sr + p * 16) * XS_STRIDE + sc4] = v;
        }
        {
            const float4* Wv = (const float4*)(W1 + half * 64 * FH);
            float4* wv = (float4*)ws;
            for (int i = t; i < 64 * FH / 4; i += 256) wv[i] = Wv[i];
        }
        __syncthreads();
#pragma unroll 2
        for (int k = 0; k < 64; k += 4) {
            float4 a0 = *(const float4*)&xs[(ty4 + 0) * XS_STRIDE + k];
            float4 a1 = *(const float4*)&xs[(ty4 + 1) * XS_STRIDE + k];
            float4 a2 = *(const float4*)&xs[(ty4 + 2) * XS_STRIDE + k];
            float4 a3 = *(const float4*)&xs[(ty4 + 3) * XS_STRIDE + k];
            float4 b0 = *(const float4*)&ws[(k + 0) * FH + tx4];
            float4 b1 = *(const float4*)&ws[(k + 1) * FH + tx4];
            float4 b2 = *(const float4*)&ws[(k + 2) * FH + tx4];
            float4 b3 = *(const float4*)&ws[(k + 3) * FH + tx4];
#define KK1(AE, BV) \
            acc[0][0] = fmaf(a0.AE, BV.x, acc[0][0]); \
            acc[0][1] = fmaf(a0.AE, BV.y, acc[0][1]); \
            acc[0][2] = fmaf(a0.AE, BV.z, acc[0][2]); \
            acc[0][3] = fmaf(a0.AE, BV.w, acc[0][3]); \
            acc[1][0] = fmaf(a1.AE, BV.x, acc[1][0]); \
            acc[1][1] = fmaf(a1.AE, BV.y, acc[1][1]); \
            acc[1][2] = fmaf(a1.AE, BV.z, acc[1][2]); \
            acc[1][3] = fmaf(a1.AE, BV.w, acc[1][3]); \
            acc[2][0] = fmaf(a2.AE, BV.x, acc[2][0]); \
            acc[2][1] = fmaf(a2.AE, BV.y, acc[2][1]); \
            acc[2][2] = fmaf(a2.AE, BV.z, acc[2][2]); \
            acc[2][3] = fmaf(a2.AE, BV.w, acc[2][3]); \
            acc[3][0] = fmaf(a3.AE, BV.x, acc[3][0]); \
            acc[3][1] = fmaf(a3.AE, BV.y, acc[3][1]); \
            acc[3][2] = fmaf(a3.AE, BV.z, acc[3][2]); \
            acc[3][3] = fmaf(a3.AE, BV.w, acc[3][3]);
            KK1(x, b0) KK1(y, b1) KK1(z, b2) KK1(w, b3)
#undef KK1
        }
    }
#pragma unroll
    for (int i = 0; i < 4; ++i) {
        int row = row0 + ty4 + i;
        if (row < NN) {
            float s = inv[row];
            union { f16 h[4]; uint2 u; } p;
            p.h[0] = (f16)(acc[i][0] * s);
            p.h[1] = (f16)(acc[i][1] * s);
            p.h[2] = (f16)(acc[i][2] * s);
            p.h[3] = (f16)(acc[i][3] * s);
            *(uint2*)&h0s[(size_t)row * FH + tx4] = p.u;
        } else if (row == NN) {
            *(uint2*)&h0s[(size_t)row * FH + tx4] = make_uint2(0u, 0u);
        }
    }
}

// ---------------- agg1: quad-parity gather + precomputed-mask epilogue -----
__global__ __launch_bounds__(256) void k_agg1(const int2* __restrict__ odpk,
                                              const int* __restrict__ csr_s,
                                              const float* __restrict__ inv,
                                              const f16* __restrict__ h0s,
                                              const float* __restrict__ b1,
                                              const unsigned long long* __restrict__ dm,
                                              f16* __restrict__ h1s) {
    int lane = threadIdx.x & 63;
    int d = __builtin_amdgcn_readfirstlane((int)(blockIdx.x * 4 + (threadIdx.x >> 6)));
    if (d >= NN) return;
    int p = lane >> 4;
    int c4 = (lane & 15) * 4;
    size_t q8 = (size_t)(lane & 15) * 8;       // byte offset within row
    const char* hb = (const char*)h0s;
    int2 od = odpk[d];
    int start = od.x, degp = od.y;             // degp % 4 == 0 (padded)
    float a0 = 0.f, a1 = 0.f, a2 = 0.f, a3 = 0.f;
    int k = 0;
    for (; k + 8 <= degp; k += 8) {
        int s0 = csr_s[start + k + 0], s1 = csr_s[start + k + 1];
        int s2 = csr_s[start + k + 2], s3 = csr_s[start + k + 3];
        int s4 = csr_s[start + k + 4], s5 = csr_s[start + k + 5];
        int s6 = csr_s[start + k + 6], s7 = csr_s[start + k + 7];
        int ia = sel4(p, s0, s1, s2, s3);
        int ib = sel4(p, s4, s5, s6, s7);
        union { uint2 u; f16x2 h[2]; } A, B;
        A.u = *(const uint2*)(hb + ((size_t)ia << 7) + q8);
        B.u = *(const uint2*)(hb + ((size_t)ib << 7) + q8);
        f16x2 p0 = A.h[0] + B.h[0];            // v_pk_add_f16
        f16x2 p1 = A.h[1] + B.h[1];
        a0 += (float)p0[0]; a1 += (float)p0[1];
        a2 += (float)p1[0]; a3 += (float)p1[1];
    }
    if (k < degp) {                            // exactly 4 remain
        int s0 = csr_s[start + k + 0], s1 = csr_s[start + k + 1];
        int s2 = csr_s[start + k + 2], s3 = csr_s[start + k + 3];
        int ia = sel4(p, s0, s1, s2, s3);
        uint2 ua = *(const uint2*)(hb + ((size_t)ia << 7) + q8);
        float f0, f1, f2, f3;
        unpack2(ua.x, f0, f1); unpack2(ua.y, f2, f3);
        a0 += f0; a1 += f1; a2 += f2; a3 += f3;
    }
    // combine 4 parities (f32 butterflies — independent pairs dual-issue)
    a0 += __shfl_xor(a0, 16, 64); a0 += __shfl_xor(a0, 32, 64);
    a1 += __shfl_xor(a1, 16, 64); a1 += __shfl_xor(a1, 32, 64);
    a2 += __shfl_xor(a2, 16, 64); a2 += __shfl_xor(a2, 32, 64);
    a3 += __shfl_xor(a3, 16, 64); a3 += __shfl_xor(a3, 32, 64);
    // self + bias + relu
    float invd = inv[d];
    uint2 su = *(const uint2*)(hb + ((size_t)d << 7) + q8);
    float s0, s1, s2, s3;
    unpack2(su.x, s0, s1); unpack2(su.y, s2, s3);
    float4 bv = *(const float4*)&b1[c4];
    float v0 = fmaxf((a0 + s0) * invd + bv.x, 0.f);
    float v1 = fmaxf((a1 + s1) * invd + bv.y, 0.f);
    float v2 = fmaxf((a2 + s2) * invd + bv.z, 0.f);
    float v3 = fmaxf((a3 + s3) * invd + bv.w, 0.f);
    // dropout: precomputed mask (wave-uniform s_load)
    unsigned long long m = dm[d];
    unsigned mm = (unsigned)(m >> c4) & 15u;   // keep bits for c4..c4+3
    if (lane < 16) {
        union { f16 h[4]; uint2 u; } st;
        st.h[0] = (f16)((mm & 1u) ? v0 * 2.f : 0.f);
        st.h[1] = (f16)((mm & 2u) ? v1 * 2.f : 0.f);
        st.h[2] = (f16)((mm & 4u) ? v2 * 2.f : 0.f);
        st.h[3] = (f16)((mm & 8u) ? v3 * 2.f : 0.f);
        *(uint2*)&h1s[(size_t)d * FH + c4] = st.u;
    }
}

// ---------------- GEMM2: h2s[N,64pad] = (h1s @ W2) * inv[row] (f16 in/out) -
#define HS_STRIDE 68    // 64 + 4: b128-aligned, rows on distinct banks
__global__ __launch_bounds__(256) void k_gemm2(const f16* __restrict__ h1s,
                                               const float* __restrict__ W2,
                                               const float* __restrict__ inv,
                                               f16* __restrict__ h2s) {
    __shared__ float hs[64 * HS_STRIDE];   // 17.4 KB
    __shared__ float ws[FH * 64];          // 16 KB, cols 40..63 zero
    int t = threadIdx.x;
    int row0 = blockIdx.x * 64;
    {
        int r = t >> 4;              // 0..15
        int c4 = (t & 15) * 4;       // 0..60
#pragma unroll
        for (int p = 0; p < 4; ++p) {
            int row = row0 + r + p * 16;
            float4 v = make_float4(0.f, 0.f, 0.f, 0.f);
            if (row < NN) {
                uint2 u = *(const uint2*)&h1s[(size_t)row * FH + c4];
                unpack2(u.x, v.x, v.y);
                unpack2(u.y, v.z, v.w);
            }
            *(float4*)&hs[(r + p * 16) * HS_STRIDE + c4] = v;
        }
    }
    for (int i = t; i < FH * 64; i += 256) {
        int r = i >> 6, c = i & 63;
        ws[i] = (c < FO) ? W2[r * FO + c] : 0.f;
    }
    __syncthreads();
    float acc[4][4] = {{0.f}};
    int tx4 = (t & 15) * 4;
    int ty4 = (t >> 4) * 4;
#pragma unroll 2
    for (int k = 0; k < FH; k += 4) {
        float4 a0 = *(const float4*)&hs[(ty4 + 0) * HS_STRIDE + k];
        float4 a1 = *(const float4*)&hs[(ty4 + 1) * HS_STRIDE + k];
        float4 a2 = *(const float4*)&hs[(ty4 + 2) * HS_STRIDE + k];
        float4 a3 = *(const float4*)&hs[(ty4 + 3) * HS_STRIDE + k];
        float4 b0 = *(const float4*)&ws[(k + 0) * 64 + tx4];
        float4 b1 = *(const float4*)&ws[(k + 1) * 64 + tx4];
        float4 b2 = *(const float4*)&ws[(k + 2) * 64 + tx4];
        float4 b3 = *(const float4*)&ws[(k + 3) * 64 + tx4];
#define KK2(AE, BV) \
        acc[0][0] = fmaf(a0.AE, BV.x, acc[0][0]); \
        acc[0][1] = fmaf(a0.AE, BV.y, acc[0][1]); \
        acc[0][2] = fmaf(a0.AE, BV.z, acc[0][2]); \
        acc[0][3] = fmaf(a0.AE, BV.w, acc[0][3]); \
        acc[1][0] = fmaf(a1.AE, BV.x, acc[1][0]); \
        acc[1][1] = fmaf(a1.AE, BV.y, acc[1][1]); \
        acc[1][2] = fmaf(a1.AE, BV.z, acc[1][2]); \
        acc[1][3] = fmaf(a1.AE, BV.w, acc[1][3]); \
        acc[2][0] = fmaf(a2.AE, BV.x, acc[2][0]); \
        acc[2][1] = fmaf(a2.AE, BV.y, acc[2][1]); \
        acc[2][2] = fmaf(a2.AE, BV.z, acc[2][2]); \
        acc[2][3] = fmaf(a2.AE, BV.w, acc[2][3]); \
        acc[3][0] = fmaf(a3.AE, BV.x, acc[3][0]); \
        acc[3][1] = fmaf(a3.AE, BV.y, acc[3][1]); \
        acc[3][2] = fmaf(a3.AE, BV.z, acc[3][2]); \
        acc[3][3] = fmaf(a3.AE, BV.w, acc[3][3]);
        KK2(x, b0) KK2(y, b1) KK2(z, b2) KK2(w, b3)
#undef KK2
    }
#pragma unroll
    for (int i = 0; i < 4; ++i) {
        int row = row0 + ty4 + i;
        if (row < NN) {
            float s = inv[row];
            union { f16 h[4]; uint2 u; } p;
            p.h[0] = (f16)(acc[i][0] * s);
            p.h[1] = (f16)(acc[i][1] * s);
            p.h[2] = (f16)(acc[i][2] * s);
            p.h[3] = (f16)(acc[i][3] * s);
            *(uint2*)&h2s[(size_t)row * FH + tx4] = p.u;
        } else if (row == NN) {
            *(uint2*)&h2s[(size_t)row * FH + tx4] = make_uint2(0u, 0u);
        }
    }
}

// ---------------- agg2: quad-parity gather (pk_add_f16) + self + b2 --------
__global__ __launch_bounds__(256) void k_agg2(const int2* __restrict__ odpk,
                                              const int* __restrict__ csr_s,
                                              const float* __restrict__ inv,
                                              const f16* __restrict__ h2s,
                                              const float* __restrict__ b2,
                                              float* __restrict__ out) {
    int lane = threadIdx.x & 63;
    int d = __builtin_amdgcn_readfirstlane((int)(blockIdx.x * 4 + (threadIdx.x >> 6)));
    if (d >= NN) return;
    int p = lane >> 4;
    int c4 = (lane & 15) * 4;
    size_t q8 = (size_t)(lane & 15) * 8;
    const char* hb = (const char*)h2s;
    int2 od = odpk[d];
    int start = od.x, degp = od.y;
    float a0 = 0.f, a1 = 0.f, a2 = 0.f, a3 = 0.f;
    int k = 0;
    for (; k + 8 <= degp; k += 8) {
        int s0 = csr_s[start + k + 0], s1 = csr_s[start + k + 1];
        int s2 = csr_s[start + k + 2], s3 = csr_s[start + k + 3];
        int s4 = csr_s[start + k + 4], s5 = csr_s[start + k + 5];
        int s6 = csr_s[start + k + 6], s7 = csr_s[start + k + 7];
        int ia = sel4(p, s0, s1, s2, s3);
        int ib = sel4(p, s4, s5, s6, s7);
        union { uint2 u; f16x2 h[2]; } A, B;
        A.u = *(const uint2*)(hb + ((size_t)ia << 7) + q8);
        B.u = *(const uint2*)(hb + ((size_t)ib << 7) + q8);
        f16x2 p0 = A.h[0] + B.h[0];            // v_pk_add_f16
        f16x2 p1 = A.h[1] + B.h[1];
        a0 += (float)p0[0]; a1 += (float)p0[1];
        a2 += (float)p1[0]; a3 += (float)p1[1];
    }
    if (k < degp) {
        int s0 = csr_s[start + k + 0], s1 = csr_s[start + k + 1];
        int s2 = csr_s[start + k + 2], s3 = csr_s[start + k + 3];
        int ia = sel4(p, s0, s1, s2, s3);
        uint2 ua = *(const uint2*)(hb + ((size_t)ia << 7) + q8);
        float f0, f1, f2, f3;
        unpack2(ua.x, f0, f1); unpack2(ua.y, f2, f3);
        a0 += f0; a1 += f1; a2 += f2; a3 += f3;
    }
    a0 += __shfl_xor(a0, 16, 64); a0 += __shfl_xor(a0, 32, 64);
    a1 += __shfl_xor(a1, 16, 64); a1 += __shfl_xor(a1, 32, 64);
    a2 += __shfl_xor(a2, 16, 64); a2 += __shfl_xor(a2, 32, 64);
    a3 += __shfl_xor(a3, 16, 64); a3 += __shfl_xor(a3, 32, 64);
    if (lane < 10) {                           // c4 <= 36 -> cols 0..39
        float invd = inv[d];
        uint2 su = *(const uint2*)(hb + ((size_t)d << 7) + q8);
        float s0, s1, s2, s3;
        unpack2(su.x, s0, s1); unpack2(su.y, s2, s3);
        float4 bv = *(const float4*)&b2[c4];
        float4 st;
        st.x = (a0 + s0) * invd + bv.x;
        st.y = (a1 + s1) * invd + bv.y;
        st.z = (a2 + s2) * invd + bv.z;
        st.w = (a3 + s3) * invd + bv.w;
        *(float4*)&out[(size_t)d * FO + c4] = st;
    }
}

extern "C" void kernel_launch(void* const* d_in, const int* in_sizes, int n_in,
                              void* d_out, int out_size, void* d_ws, size_t ws_size,
                              hipStream_t stream) {
    const float* x  = (const float*)d_in[0];
    const int*   ei = (const int*)d_in[1];   // int32 [2, NE]: src = ei[e], dst = ei[NE+e]
    const float* W1 = (const float*)d_in[2];
    const float* b1 = (const float*)d_in[3];
    const float* W2 = (const float*)d_in[4];
    const float* b2 = (const float*)d_in[5];
    float* out = (float*)d_out;

    char* ws = (char*)d_ws;
    int*   blkhist   = (int*)ws;                                  // 1.0 MB
    int*   rtot      = (int*)(ws + (size_t)(1 << 20) + 102400);   // 2 KB
    int*   rangeBase = (int*)(ws + (size_t)(1 << 20) + 106496);   // 2 KB (501)
    float* inv       = (float*)(ws + (size_t)( 2 << 20));         // 0.4 MB
    int2*  odpk      = (int2*)(ws + (size_t)( 3 << 20));          // 0.8 MB
    int*   bucket    = (int*)(ws + (size_t)( 4 << 20));           // 6.4 MB (packed; dead after p3)
    f16*   h2s       = (f16*)(ws + (size_t)( 4 << 20));           // 12.8 MB (reuses bucket region)
    int*   csr_s     = (int*)(ws + (size_t)(17 << 20));           // <=7.6 MB (padded)
    f16*   h0s       = (f16*)(ws + (size_t)(25 << 20));           // 12.8 MB (+row NN)
    f16*   h1s       = (f16*)(ws + (size_t)(38 << 20));           // 12.8 MB
    unsigned long long* dm = (unsigned long long*)(ws + (size_t)(51 << 20));  // 0.8 MB

    k_mask<<<NN * FH / 256, 256, 0, stream>>>(dm);
    k_p1<<<NBK, 256, 0, stream>>>(ei, blkhist);
    k_scanR1<<<NR, 512, 0, stream>>>(blkhist, rtot);
    k_scanR2<<<1, 512, 0, stream>>>(rtot, rangeBase);
    k_p2<<<NBK, 256, 0, stream>>>(ei, blkhist, rangeBase, bucket);
    k_p3<<<NR, 256, 0, stream>>>(bucket, rangeBase, odpk, inv, csr_s);

    int gblk = (NN + 63) / 64;   // 1563 (covers zero row NN at row0=99968..100031)
    k_gemm1<<<gblk, 256, 0, stream>>>(x, W1, inv, h0s);
    k_agg1<<<NN / 4, 256, 0, stream>>>(odpk, csr_s, inv, h0s, b1, dm, h1s);

    k_gemm2<<<gblk, 256, 0, stream>>>(h1s, W2, inv, h2s);
    k_agg2<<<NN / 4, 256, 0, stream>>>(odpk, csr_s, inv, h2s, b2, out);
}

// Round 22
// 177.280 us; speedup vs baseline: 1.0496x; 1.0496x over previous
//
#include <hip/hip_runtime.h>

#define NN 100000
#define NE 1600000
#define FI 128
#define FH 64
#define FO 40
#define NR 500      // dst ranges
#define RSZ 200     // nodes per range (NR*RSZ == NN)
#define NBK 512     // histogram/scatter blocks

typedef _Float16 f16;
typedef _Float16 f16x2 __attribute__((ext_vector_type(2)));
typedef _Float16 v8h __attribute__((ext_vector_type(8)));
typedef float v4f __attribute__((ext_vector_type(4)));

// ---------------- Threefry-2x32, key = (0, 42) -----------------------------
__device__ __forceinline__ unsigned rotl32(unsigned v, unsigned r) {
    return (v << r) | (v >> (32u - r));
}

__device__ __forceinline__ void threefry_0_42(unsigned x0, unsigned x1,
                                              unsigned& o0, unsigned& o1) {
    const unsigned k0 = 0u, k1 = 42u;
    const unsigned k2 = 0x1BD11BDAu ^ k0 ^ k1;
    x0 += k0; x1 += k1;
#define TFR(r) { x0 += x1; x1 = rotl32(x1, r); x1 ^= x0; }
    TFR(13) TFR(15) TFR(26) TFR(6)   x0 += k1; x1 += k2 + 1u;
    TFR(17) TFR(29) TFR(16) TFR(24)  x0 += k2; x1 += k0 + 2u;
    TFR(13) TFR(15) TFR(26) TFR(6)   x0 += k0; x1 += k1 + 3u;
    TFR(17) TFR(29) TFR(16) TFR(24)  x0 += k1; x1 += k2 + 4u;
    TFR(13) TFR(15) TFR(26) TFR(6)   x0 += k2; x1 += k0 + 5u;
#undef TFR
    o0 = x0; o1 = x1;
}

__device__ __forceinline__ void unpack2(unsigned u, float& lo, float& hi) {
    union { unsigned u; f16 h[2]; } c;
    c.u = u;
    lo = (float)c.h[0];
    hi = (float)c.h[1];
}

// select one of 4 wave-uniform values by per-lane parity p (0..3)
__device__ __forceinline__ int sel4(int p, int s0, int s1, int s2, int s3) {
    int t0 = (p & 1) ? s1 : s0;
    int t1 = (p & 1) ? s3 : s2;
    return (p & 2) ? t1 : t0;
}

// ---------------- k_mask: precompute dropout keep-mask (u64 per node) ------
__global__ __launch_bounds__(256) void k_mask(unsigned long long* __restrict__ dm) {
    int tid = blockIdx.x * 256 + threadIdx.x;   // element = node*64 + feature
    unsigned o0, o1;
    threefry_0_42(0u, (unsigned)tid, o0, o1);
    unsigned long long m = __ballot((int)(((o0 ^ o1) >> 31) ^ 1u));
    if ((threadIdx.x & 63) == 0) dm[tid >> 6] = m;
}

// ---------------- P1: per-block LDS range histogram (2 edges/thread) -------
__global__ __launch_bounds__(256) void k_p1(const int* __restrict__ ei,
                                            int* __restrict__ blkhist) {
    __shared__ int h[NR];
    int t = threadIdx.x, b = blockIdx.x;
    for (int i = t; i < NR; i += 256) h[i] = 0;
    __syncthreads();
    for (int base = b * 512 + t * 2; base < NE; base += NBK * 512) {
        int2 dd = *(const int2*)&ei[NE + base];
        atomicAdd(&h[dd.x / RSZ], 1);            // LDS atomic
        atomicAdd(&h[dd.y / RSZ], 1);
    }
    __syncthreads();
    for (int i = t; i < NR; i += 256) blkhist[(size_t)b * NR + i] = h[i];
}

// ---------------- scanR1: per-range exclusive scan over blocks -------------
__global__ __launch_bounds__(512) void k_scanR1(int* __restrict__ blkhist,
                                                int* __restrict__ rtot) {
    __shared__ int sh[NBK];
    int r = blockIdx.x, t = threadIdx.x;
    int v = blkhist[(size_t)t * NR + r];
    sh[t] = v;
    __syncthreads();
    for (int off = 1; off < NBK; off <<= 1) {
        int u = (t >= off) ? sh[t - off] : 0;
        __syncthreads();
        sh[t] += u;
        __syncthreads();
    }
    blkhist[(size_t)t * NR + r] = sh[t] - v;     // block-local prefix
    if (t == NBK - 1) rtot[r] = sh[t];
}

// ---------------- scanR2: exclusive scan of range totals -------------------
__global__ __launch_bounds__(512) void k_scanR2(const int* __restrict__ rtot,
                                                int* __restrict__ rangeBase) {
    __shared__ int sh[512];
    int t = threadIdx.x;
    int v = (t < NR) ? rtot[t] : 0;
    sh[t] = v;
    __syncthreads();
    for (int off = 1; off < 512; off <<= 1) {
        int u = (t >= off) ? sh[t - off] : 0;
        __syncthreads();
        sh[t] += u;
        __syncthreads();
    }
    if (t < NR) rangeBase[t] = sh[t] - v;
    if (t == NR - 1) rangeBase[NR] = sh[t];      // == NE
}

// ---------------- P2: scatter edges, packed 4B (dloc<<17 | src) ------------
__global__ __launch_bounds__(256) void k_p2(const int* __restrict__ ei,
                                            const int* __restrict__ blkhist,
                                            const int* __restrict__ rangeBase,
                                            int* __restrict__ bucket) {
    __shared__ int cur[NR];
    int t = threadIdx.x, b = blockIdx.x;
    for (int i = t; i < NR; i += 256)
        cur[i] = rangeBase[i] + blkhist[(size_t)b * NR + i];
    __syncthreads();
    for (int base = b * 512 + t * 2; base < NE; base += NBK * 512) {  // same slice as k_p1
        int2 ss = *(const int2*)&ei[base];
        int2 dd = *(const int2*)&ei[NE + base];
        int rg0 = dd.x / RSZ;
        int rg1 = dd.y / RSZ;
        int pos0 = atomicAdd(&cur[rg0], 1);               // LDS atomic
        bucket[pos0] = ((dd.x - rg0 * RSZ) << 17) | ss.x;
        int pos1 = atomicAdd(&cur[rg1], 1);
        bucket[pos1] = ((dd.y - rg1 * RSZ) << 17) | ss.y;
    }
}

// ---------------- P3: per-range CSR finalize, segments padded to x4 --------
// Padded entries point to src = NN (all-zero feature row) -> tail-free agg.
__global__ __launch_bounds__(256) void k_p3(const int* __restrict__ bucket,
                                            const int* __restrict__ rangeBase,
                                            int2* __restrict__ odpk,
                                            float* __restrict__ inv,
                                            int* __restrict__ csr_s) {
    __shared__ int cnt[RSZ];
    __shared__ int base[RSZ];
    __shared__ int sc[256];
    int r = blockIdx.x, t = threadIdx.x;
    int e0 = rangeBase[r], e1 = rangeBase[r + 1];
    int padBase = e0 + 3 * RSZ * r;                       // padded global base
    int n0 = r * RSZ;
    if (t < RSZ) cnt[t] = 0;
    __syncthreads();
    for (int i = e0 + t; i < e1; i += 256)
        atomicAdd(&cnt[((unsigned)bucket[i]) >> 17], 1);  // LDS atomic
    __syncthreads();
    int v = 0, vp = 0;
    if (t < RSZ) {
        v = cnt[t];
        vp = (v + 3) & ~3;                                // padded count
    }
    sc[t] = vp;
    __syncthreads();
    for (int off = 1; off < 256; off <<= 1) {
        int u = (t >= off) ? sc[t - off] : 0;
        __syncthreads();
        sc[t] += u;
        __syncthreads();
    }
    int o = 0;
    if (t < RSZ) {
        o = padBase + sc[t] - vp;                         // padded CSR offset
        odpk[n0 + t] = make_int2(o, vp);                  // loop bound = padded
        inv[n0 + t] = rsqrtf((float)v + 1.0f);            // norm from real deg
        base[t] = o;                                      // cursor start
    }
    __syncthreads();
    for (int i = e0 + t; i < e1; i += 256) {
        int pk = bucket[i];
        int dloc = ((unsigned)pk) >> 17;
        int p = atomicAdd(&base[dloc], 1);                // LDS atomic
        csr_s[p] = pk & 0x1FFFF;
    }
    __syncthreads();
    if (t < RSZ) {
        for (int j = v; j < vp; ++j) csr_s[o + j] = NN;   // sentinel pads
    }
}

// ---------------- GEMM1 (MFMA): h0s[N,64] = (x @ W1) * inv[row] (f16 out) --
// 4 waves/block, 16 rows/wave, 64 cols. Fragments pre-swizzled in LDS.
// A frag: lane l, elem j -> x[row0+16w+(l&15)][32ks + 16*(j>>2) + 4*(l>>4) + (j&3)]
// B frag: lane l, elem j -> W1[32ks + 16*(j>>2) + 4*(l>>4) + (j&3)][16n + (l&15)]
// C/D:   col = l&15, row = (l>>4)*4 + reg   [guide-verified]
__global__ __launch_bounds__(256) void k_gemm1(const float* __restrict__ x,
                                               const float* __restrict__ W1,
                                               const float* __restrict__ inv,
                                               f16* __restrict__ h0s) {
    __shared__ f16 afrag[16 * 64 * 8];   // [w*4+ks][lane][8] = 16 KB
    __shared__ f16 wfrag[16 * 64 * 8];   // [ks*4+n][lane][8] = 16 KB
    int t = threadIdx.x;
    int row0 = blockIdx.x * 64;
    // ---- stage A fragments (x tile, fp32 -> f16, scattered ds_write_b16) --
    {
        int r = t >> 5;               // 0..7
        int c0 = (t & 31) * 4;        // 0..124
#pragma unroll
        for (int pp = 0; pp < 8; ++pp) {
            int rr = r + pp * 8;      // 0..63
            int row = row0 + rr;
            float4 v = make_float4(0.f, 0.f, 0.f, 0.f);
            if (row < NN) v = *(const float4*)&x[(size_t)row * FI + c0];
            int w = rr >> 4, rl = rr & 15;
            float vv[4] = {v.x, v.y, v.z, v.w};
#pragma unroll
            for (int e = 0; e < 4; ++e) {
                int c = c0 + e;
                int ks = c >> 5, kl = c & 31;
                int j = ((kl >> 4) << 2) | (kl & 3);
                int grp = (kl >> 2) & 3;
                afrag[(((w * 4 + ks) * 64) + grp * 16 + rl) * 8 + j] = (f16)vv[e];
            }
        }
    }
    // ---- stage B fragments (W1 128x64, fp32 -> f16) ------------------------
    {
        int k = t >> 4;               // 0..15
        int c0 = (t & 15) * 4;        // 0..60
#pragma unroll
        for (int pp = 0; pp < 8; ++pp) {
            int kk = k + pp * 16;     // 0..127
            float4 v = *(const float4*)&W1[kk * FH + c0];
            int ks = kk >> 5, kl = kk & 31;
            int j = ((kl >> 4) << 2) | (kl & 3);
            int grp = (kl >> 2) & 3;
            float vv[4] = {v.x, v.y, v.z, v.w};
#pragma unroll
            for (int e = 0; e < 4; ++e) {
                int c = c0 + e;
                int n = c >> 4, ll = c & 15;
                wfrag[(((ks * 4 + n) * 64) + grp * 16 + ll) * 8 + j] = (f16)vv[e];
            }
        }
    }
    __syncthreads();
    int l = t & 63, w = t >> 6;
    v4f acc[4] = {{0.f,0.f,0.f,0.f},{0.f,0.f,0.f,0.f},{0.f,0.f,0.f,0.f},{0.f,0.f,0.f,0.f}};
#pragma unroll
    for (int ks = 0; ks < 4; ++ks) {
        v8h a = *(const v8h*)&afrag[((w * 4 + ks) * 64 + l) * 8];
#pragma unroll
        for (int n = 0; n < 4; ++n) {
            v8h b = *(const v8h*)&wfrag[((ks * 4 + n) * 64 + l) * 8];
            acc[n] = __builtin_amdgcn_mfma_f32_16x16x32_f16(a, b, acc[n], 0, 0, 0);
        }
    }
    // ---- epilogue ----------------------------------------------------------
    int colb = l & 15, rgrp = l >> 4;
#pragma unroll
    for (int r = 0; r < 4; ++r) {
        int row = row0 + 16 * w + rgrp * 4 + r;
        if (row <= NN) {
            float s = (row < NN) ? inv[row] : 0.f;   // row NN -> zeros
#pragma unroll
            for (int n = 0; n < 4; ++n)
                h0s[(size_t)row * FH + n * 16 + colb] = (f16)(acc[n][r] * s);
        }
    }
}

// ---------------- agg1: quad-parity gather + precomputed-mask epilogue -----
__global__ __launch_bounds__(256) void k_agg1(const int2* __restrict__ odpk,
                                              const int* __restrict__ csr_s,
                                              const float* __restrict__ inv,
                                              const f16* __restrict__ h0s,
                                              const float* __restrict__ b1,
                                              const unsigned long long* __restrict__ dm,
                                              f16* __restrict__ h1s) {
    int lane = threadIdx.x & 63;
    int d = __builtin_amdgcn_readfirstlane((int)(blockIdx.x * 4 + (threadIdx.x >> 6)));
    if (d >= NN) return;
    int p = lane >> 4;
    int c4 = (lane & 15) * 4;
    size_t q8 = (size_t)(lane & 15) * 8;       // byte offset within row
    const char* hb = (const char*)h0s;
    int2 od = odpk[d];
    int start = od.x, degp = od.y;             // degp % 4 == 0 (padded)
    float a0 = 0.f, a1 = 0.f, a2 = 0.f, a3 = 0.f;
    int k = 0;
    for (; k + 8 <= degp; k += 8) {
        int s0 = csr_s[start + k + 0], s1 = csr_s[start + k + 1];
        int s2 = csr_s[start + k + 2], s3 = csr_s[start + k + 3];
        int s4 = csr_s[start + k + 4], s5 = csr_s[start + k + 5];
        int s6 = csr_s[start + k + 6], s7 = csr_s[start + k + 7];
        int ia = sel4(p, s0, s1, s2, s3);
        int ib = sel4(p, s4, s5, s6, s7);
        union { uint2 u; f16x2 h[2]; } A, B;
        A.u = *(const uint2*)(hb + ((size_t)ia << 7) + q8);
        B.u = *(const uint2*)(hb + ((size_t)ib << 7) + q8);
        f16x2 p0 = A.h[0] + B.h[0];            // v_pk_add_f16
        f16x2 p1 = A.h[1] + B.h[1];
        a0 += (float)p0[0]; a1 += (float)p0[1];
        a2 += (float)p1[0]; a3 += (float)p1[1];
    }
    if (k < degp) {                            // exactly 4 remain
        int s0 = csr_s[start + k + 0], s1 = csr_s[start + k + 1];
        int s2 = csr_s[start + k + 2], s3 = csr_s[start + k + 3];
        int ia = sel4(p, s0, s1, s2, s3);
        uint2 ua = *(const uint2*)(hb + ((size_t)ia << 7) + q8);
        float f0, f1, f2, f3;
        unpack2(ua.x, f0, f1); unpack2(ua.y, f2, f3);
        a0 += f0; a1 += f1; a2 += f2; a3 += f3;
    }
    // combine 4 parities (f32 butterflies — independent pairs dual-issue)
    a0 += __shfl_xor(a0, 16, 64); a0 += __shfl_xor(a0, 32, 64);
    a1 += __shfl_xor(a1, 16, 64); a1 += __shfl_xor(a1, 32, 64);
    a2 += __shfl_xor(a2, 16, 64); a2 += __shfl_xor(a2, 32, 64);
    a3 += __shfl_xor(a3, 16, 64); a3 += __shfl_xor(a3, 32, 64);
    // self + bias + relu
    float invd = inv[d];
    uint2 su = *(const uint2*)(hb + ((size_t)d << 7) + q8);
    float s0, s1, s2, s3;
    unpack2(su.x, s0, s1); unpack2(su.y, s2, s3);
    float4 bv = *(const float4*)&b1[c4];
    float v0 = fmaxf((a0 + s0) * invd + bv.x, 0.f);
    float v1 = fmaxf((a1 + s1) * invd + bv.y, 0.f);
    float v2 = fmaxf((a2 + s2) * invd + bv.z, 0.f);
    float v3 = fmaxf((a3 + s3) * invd + bv.w, 0.f);
    // dropout: precomputed mask (wave-uniform s_load)
    unsigned long long m = dm[d];
    unsigned mm = (unsigned)(m >> c4) & 15u;   // keep bits for c4..c4+3
    if (lane < 16) {
        union { f16 h[4]; uint2 u; } st;
        st.h[0] = (f16)((mm & 1u) ? v0 * 2.f : 0.f);
        st.h[1] = (f16)((mm & 2u) ? v1 * 2.f : 0.f);
        st.h[2] = (f16)((mm & 4u) ? v2 * 2.f : 0.f);
        st.h[3] = (f16)((mm & 8u) ? v3 * 2.f : 0.f);
        *(uint2*)&h1s[(size_t)d * FH + c4] = st.u;
    }
}

// ---------------- GEMM2: h2s[N,64pad] = (h1s @ W2) * inv[row] (f16 in/out) -
#define HS_STRIDE 68    // 64 + 4: b128-aligned, rows on distinct banks
__global__ __launch_bounds__(256) void k_gemm2(const f16* __restrict__ h1s,
                                               const float* __restrict__ W2,
                                               const float* __restrict__ inv,
                                               f16* __restrict__ h2s) {
    __shared__ float hs[64 * HS_STRIDE];   // 17.4 KB
    __shared__ float ws[FH * 64];          // 16 KB, cols 40..63 zero
    int t = threadIdx.x;
    int row0 = blockIdx.x * 64;
    {
        int r = t >> 4;              // 0..15
        int c4 = (t & 15) * 4;       // 0..60
#pragma unroll
        for (int p = 0; p < 4; ++p) {
            int row = row0 + r + p * 16;
            float4 v = make_float4(0.f, 0.f, 0.f, 0.f);
            if (row < NN) {
                uint2 u = *(const uint2*)&h1s[(size_t)row * FH + c4];
                unpack2(u.x, v.x, v.y);
                unpack2(u.y, v.z, v.w);
            }
            *(float4*)&hs[(r + p * 16) * HS_STRIDE + c4] = v;
        }
    }
    for (int i = t; i < FH * 64; i += 256) {
        int r = i >> 6, c = i & 63;
        ws[i] = (c < FO) ? W2[r * FO + c] : 0.f;
    }
    __syncthreads();
    float acc[4][4] = {{0.f}};
    int tx4 = (t & 15) * 4;
    int ty4 = (t >> 4) * 4;
#pragma unroll 2
    for (int k = 0; k < FH; k += 4) {
        float4 a0 = *(const float4*)&hs[(ty4 + 0) * HS_STRIDE + k];
        float4 a1 = *(const float4*)&hs[(ty4 + 1) * HS_STRIDE + k];
        float4 a2 = *(const float4*)&hs[(ty4 + 2) * HS_STRIDE + k];
        float4 a3 = *(const float4*)&hs[(ty4 + 3) * HS_STRIDE + k];
        float4 b0 = *(const float4*)&ws[(k + 0) * 64 + tx4];
        float4 b1 = *(const float4*)&ws[(k + 1) * 64 + tx4];
        float4 b2 = *(const float4*)&ws[(k + 2) * 64 + tx4];
        float4 b3 = *(const float4*)&ws[(k + 3) * 64 + tx4];
#define KK2(AE, BV) \
        acc[0][0] = fmaf(a0.AE, BV.x, acc[0][0]); \
        acc[0][1] = fmaf(a0.AE, BV.y, acc[0][1]); \
        acc[0][2] = fmaf(a0.AE, BV.z, acc[0][2]); \
        acc[0][3] = fmaf(a0.AE, BV.w, acc[0][3]); \
        acc[1][0] = fmaf(a1.AE, BV.x, acc[1][0]); \
        acc[1][1] = fmaf(a1.AE, BV.y, acc[1][1]); \
        acc[1][2] = fmaf(a1.AE, BV.z, acc[1][2]); \
        acc[1][3] = fmaf(a1.AE, BV.w, acc[1][3]); \
        acc[2][0] = fmaf(a2.AE, BV.x, acc[2][0]); \
        acc[2][1] = fmaf(a2.AE, BV.y, acc[2][1]); \
        acc[2][2] = fmaf(a2.AE, BV.z, acc[2][2]); \
        acc[2][3] = fmaf(a2.AE, BV.w, acc[2][3]); \
        acc[3][0] = fmaf(a3.AE, BV.x, acc[3][0]); \
        acc[3][1] = fmaf(a3.AE, BV.y, acc[3][1]); \
        acc[3][2] = fmaf(a3.AE, BV.z, acc[3][2]); \
        acc[3][3] = fmaf(a3.AE, BV.w, acc[3][3]);
        KK2(x, b0) KK2(y, b1) KK2(z, b2) KK2(w, b3)
#undef KK2
    }
#pragma unroll
    for (int i = 0; i < 4; ++i) {
        int row = row0 + ty4 + i;
        if (row < NN) {
            float s = inv[row];
            union { f16 h[4]; uint2 u; } p;
            p.h[0] = (f16)(acc[i][0] * s);
            p.h[1] = (f16)(acc[i][1] * s);
            p.h[2] = (f16)(acc[i][2] * s);
            p.h[3] = (f16)(acc[i][3] * s);
            *(uint2*)&h2s[(size_t)row * FH + tx4] = p.u;
        } else if (row == NN) {
            *(uint2*)&h2s[(size_t)row * FH + tx4] = make_uint2(0u, 0u);
        }
    }
}

// ---------------- agg2: quad-parity gather (pk_add_f16) + self + b2 --------
__global__ __launch_bounds__(256) void k_agg2(const int2* __restrict__ odpk,
                                              const int* __restrict__ csr_s,
                                              const float* __restrict__ inv,
                                              const f16* __restrict__ h2s,
                                              const float* __restrict__ b2,
                                              float* __restrict__ out) {
    int lane = threadIdx.x & 63;
    int d = __builtin_amdgcn_readfirstlane((int)(blockIdx.x * 4 + (threadIdx.x >> 6)));
    if (d >= NN) return;
    int p = lane >> 4;
    int c4 = (lane & 15) * 4;
    size_t q8 = (size_t)(lane & 15) * 8;
    const char* hb = (const char*)h2s;
    int2 od = odpk[d];
    int start = od.x, degp = od.y;
    float a0 = 0.f, a1 = 0.f, a2 = 0.f, a3 = 0.f;
    int k = 0;
    for (; k + 8 <= degp; k += 8) {
        int s0 = csr_s[start + k + 0], s1 = csr_s[start + k + 1];
        int s2 = csr_s[start + k + 2], s3 = csr_s[start + k + 3];
        int s4 = csr_s[start + k + 4], s5 = csr_s[start + k + 5];
        int s6 = csr_s[start + k + 6], s7 = csr_s[start + k + 7];
        int ia = sel4(p, s0, s1, s2, s3);
        int ib = sel4(p, s4, s5, s6, s7);
        union { uint2 u; f16x2 h[2]; } A, B;
        A.u = *(const uint2*)(hb + ((size_t)ia << 7) + q8);
        B.u = *(const uint2*)(hb + ((size_t)ib << 7) + q8);
        f16x2 p0 = A.h[0] + B.h[0];            // v_pk_add_f16
        f16x2 p1 = A.h[1] + B.h[1];
        a0 += (float)p0[0]; a1 += (float)p0[1];
        a2 += (float)p1[0]; a3 += (float)p1[1];
    }
    if (k < degp) {
        int s0 = csr_s[start + k + 0], s1 = csr_s[start + k + 1];
        int s2 = csr_s[start + k + 2], s3 = csr_s[start + k + 3];
        int ia = sel4(p, s0, s1, s2, s3);
        uint2 ua = *(const uint2*)(hb + ((size_t)ia << 7) + q8);
        float f0, f1, f2, f3;
        unpack2(ua.x, f0, f1); unpack2(ua.y, f2, f3);
        a0 += f0; a1 += f1; a2 += f2; a3 += f3;
    }
    a0 += __shfl_xor(a0, 16, 64); a0 += __shfl_xor(a0, 32, 64);
    a1 += __shfl_xor(a1, 16, 64); a1 += __shfl_xor(a1, 32, 64);
    a2 += __shfl_xor(a2, 16, 64); a2 += __shfl_xor(a2, 32, 64);
    a3 += __shfl_xor(a3, 16, 64); a3 += __shfl_xor(a3, 32, 64);
    if (lane < 10) {                           // c4 <= 36 -> cols 0..39
        float invd = inv[d];
        uint2 su = *(const uint2*)(hb + ((size_t)d << 7) + q8);
        float s0, s1, s2, s3;
        unpack2(su.x, s0, s1); unpack2(su.y, s2, s3);
        float4 bv = *(const float4*)&b2[c4];
        float4 st;
        st.x = (a0 + s0) * invd + bv.x;
        st.y = (a1 + s1) * invd + bv.y;
        st.z = (a2 + s2) * invd + bv.z;
        st.w = (a3 + s3) * invd + bv.w;
        *(float4*)&out[(size_t)d * FO + c4] = st;
    }
}

extern "C" void kernel_launch(void* const* d_in, const int* in_sizes, int n_in,
                              void* d_out, int out_size, void* d_ws, size_t ws_size,
                              hipStream_t stream) {
    const float* x  = (const float*)d_in[0];
    const int*   ei = (const int*)d_in[1];   // int32 [2, NE]: src = ei[e], dst = ei[NE+e]
    const float* W1 = (const float*)d_in[2];
    const float* b1 = (const float*)d_in[3];
    const float* W2 = (const float*)d_in[4];
    const float* b2 = (const float*)d_in[5];
    float* out = (float*)d_out;

    char* ws = (char*)d_ws;
    int*   blkhist   = (int*)ws;                                  // 1.0 MB
    int*   rtot      = (int*)(ws + (size_t)(1 << 20) + 102400);   // 2 KB
    int*   rangeBase = (int*)(ws + (size_t)(1 << 20) + 106496);   // 2 KB (501)
    float* inv       = (float*)(ws + (size_t)( 2 << 20));         // 0.4 MB
    int2*  odpk      = (int2*)(ws + (size_t)( 3 << 20));          // 0.8 MB
    int*   bucket    = (int*)(ws + (size_t)( 4 << 20));           // 6.4 MB (packed; dead after p3)
    f16*   h2s       = (f16*)(ws + (size_t)( 4 << 20));           // 12.8 MB (reuses bucket region)
    int*   csr_s     = (int*)(ws + (size_t)(17 << 20));           // <=7.6 MB (padded)
    f16*   h0s       = (f16*)(ws + (size_t)(25 << 20));           // 12.8 MB (+rows NN..)
    f16*   h1s       = (f16*)(ws + (size_t)(38 << 20));           // 12.8 MB
    unsigned long long* dm = (unsigned long long*)(ws + (size_t)(51 << 20));  // 0.8 MB

    k_mask<<<NN * FH / 256, 256, 0, stream>>>(dm);
    k_p1<<<NBK, 256, 0, stream>>>(ei, blkhist);
    k_scanR1<<<NR, 512, 0, stream>>>(blkhist, rtot);
    k_scanR2<<<1, 512, 0, stream>>>(rtot, rangeBase);
    k_p2<<<NBK, 256, 0, stream>>>(ei, blkhist, rangeBase, bucket);
    k_p3<<<NR, 256, 0, stream>>>(bucket, rangeBase, odpk, inv, csr_s);

    int gblk = (NN + 63) / 64;   // 1563 (covers zero row NN at row0=99968..100031)
    k_gemm1<<<gblk, 256, 0, stream>>>(x, W1, inv, h0s);
    k_agg1<<<NN / 4, 256, 0, stream>>>(odpk, csr_s, inv, h0s, b1, dm, h1s);

    k_gemm2<<<gblk, 256, 0, stream>>>(h1s, W2, inv, h2s);
    k_agg2<<<NN / 4, 256, 0, stream>>>(odpk, csr_s, inv, h2s, b2, out);
}